// Round 13
// baseline (196.000 us; speedup 1.0000x reference)
//
#include <hip/hip_runtime.h>
#include <hip/hip_bf16.h>

#define HID  1024
#define N3   3072
#define NH   16
#define HD   64
#define SEQ  2048
#define NB   4
#define MTOT 8192

typedef unsigned short u16x8 __attribute__((ext_vector_type(8)));
typedef unsigned short u16x4 __attribute__((ext_vector_type(4)));
typedef float f32x4 __attribute__((ext_vector_type(4)));

static __device__ __forceinline__ unsigned short f2bf(float f) {
    union { float f; unsigned u; } v; v.f = f;
    unsigned r = (v.u + 0x7fffu + ((v.u >> 16) & 1u)) >> 16;
    return (unsigned short)r;
}

static __device__ __forceinline__ float fexp2(float x) {
    float r; asm("v_exp_f32 %0, %1" : "=v"(r) : "v"(x)); return r;
}

typedef __attribute__((address_space(3))) void* lds_vp;
typedef const __attribute__((address_space(1))) void* gbl_vp;

static __device__ __forceinline__ void gload16(const void* g, void* l) {
    __builtin_amdgcn_global_load_lds((gbl_vp)g, (lds_vp)l, 16, 0, 0);
}

// scale * log2(e), folded into GEMM1's Q columns
#define CQ 0.18033688011112042f

// ---------------- merged prep: fp32->bf16 cvt of x + two weight transposes ----
__device__ __forceinline__ void tcvt_tile(const float* __restrict__ W,
                                          unsigned short* __restrict__ WT,
                                          int R, int C, int tile, int tid,
                                          unsigned short* tilebuf) {
    int tiles_c = C >> 6;
    int k0 = (tile / tiles_c) << 6;
    int n0 = (tile % tiles_c) << 6;
    #pragma unroll
    for (int it = 0; it < 2; ++it) {
        int task = it * 256 + tid;
        int t = task >> 3, dc = task & 7;      // t: k-row, dc: n-chunk of 8
        const float* src = W + (size_t)(k0 + t) * C + n0 + dc * 8;
        float4 a = *(const float4*)src;
        float4 b = *(const float4*)(src + 4);
        u16x8 p;
        p[0]=f2bf(a.x); p[1]=f2bf(a.y); p[2]=f2bf(a.z); p[3]=f2bf(a.w);
        p[4]=f2bf(b.x); p[5]=f2bf(b.y); p[6]=f2bf(b.z); p[7]=f2bf(b.w);
        *(u16x8*)&tilebuf[t * 64 + ((dc ^ (t & 7)) << 3)] = p;
    }
    __syncthreads();
    #pragma unroll
    for (int it = 0; it < 2; ++it) {
        int task = it * 256 + tid;
        int d = task >> 3, tc = task & 7;      // d: n index (WT row), tc: k-chunk
        u16x8 p;
        #pragma unroll
        for (int i = 0; i < 8; ++i) {
            int ii = (i + tc) & 7;             // rotate to spread banks
            int t = tc * 8 + ii;
            p[ii] = tilebuf[t * 64 + ((((d >> 3) ^ (t & 7)) << 3)) + (d & 7)];
        }
        *(u16x8*)(WT + (size_t)(n0 + d) * R + k0 + tc * 8) = p;
    }
}

__global__ __launch_bounds__(256) void k_prep(const float* __restrict__ x,
                                              unsigned short* __restrict__ xb,
                                              const float* __restrict__ qkv_w,
                                              unsigned short* __restrict__ wqkvT,
                                              const float* __restrict__ proj_w,
                                              unsigned short* __restrict__ wprojT) {
    __shared__ unsigned short tilebuf[64 * 64];
    int blk = blockIdx.x, tid = threadIdx.x;
    if (blk < 4096) {
        int i = (blk * 256 + tid) * 8;
        float4 a = *(const float4*)(x + i);
        float4 b = *(const float4*)(x + i + 4);
        u16x8 p;
        p[0]=f2bf(a.x); p[1]=f2bf(a.y); p[2]=f2bf(a.z); p[3]=f2bf(a.w);
        p[4]=f2bf(b.x); p[5]=f2bf(b.y); p[6]=f2bf(b.z); p[7]=f2bf(b.w);
        *(u16x8*)(xb + i) = p;
    } else if (blk < 4864) {
        tcvt_tile(qkv_w, wqkvT, HID, N3, blk - 4096, tid, tilebuf);
    } else {
        tcvt_tile(proj_w, wprojT, HID, HID, blk - 4864, tid, tilebuf);
    }
}

// ---------------- GEMM: C[M][N] = A[M][K] * BT[N][K]^T + bias ----------------
// 256x128 tile, 8 waves (4m x 2n), BK=64, double-buffered dynamic LDS (96 KB).
// Staging skeleton (validated r12): STAGE(next) -> counted vmcnt(6) ->
// s_barrier -> compute -> __syncthreads.  NEW (r13): compute split into 4
// phases per K-tile (kk x m-half, 8 MFMA each) with s_barrier + setprio --
// T3-style ds_read||MFMA interleave.  Barriers sit in a hazard-free region
// (no LDS writes between them): scheduling-only change, cannot race.
// MODE 0: f32 output to C1 (proj GEMM)
// MODE 1: qkv split -- cols<2048 -> bf16 qkb[row][2048] (cols<1024 scaled by CQ);
//         cols>=2048 -> bf16 vT[(b*16+h)*64+d][t] (V transposed in epilogue)
template<int MODE>
__global__ __launch_bounds__(512, 2) void k_gemm(const unsigned short* __restrict__ A,
                                                 const unsigned short* __restrict__ BT,
                                                 const float* __restrict__ bias,
                                                 void* __restrict__ C1, void* __restrict__ C2,
                                                 int M, int N, int K) {
    extern __shared__ char ls[];   // [2][ A 256x64 (32KB) + B 128x64 (16KB) ]
    int tiles_n = N >> 7;
    // XCD-aware bijective swizzle (gridDim.x % 8 == 0 for all our launches)
    int bid = (blockIdx.x & 7) * (gridDim.x >> 3) + (blockIdx.x >> 3);
    int bm = bid / tiles_n, bn = bid % tiles_n;
    int tid = threadIdx.x, wid = tid >> 6, lane = tid & 63;
    int wr = wid >> 1, wc = wid & 1;
    int fr = lane & 15, fg = lane >> 4;
    int srow = lane >> 3;                    // 0..7
    int sch  = (lane & 7) ^ srow;            // swizzled k-chunk in global

    f32x4 acc[4][4];
    #pragma unroll
    for (int m = 0; m < 4; ++m)
        #pragma unroll
        for (int n = 0; n < 4; ++n)
            acc[m][n] = (f32x4){0.f, 0.f, 0.f, 0.f};

    const unsigned short* aSrc[4]; const unsigned short* bSrc[2];
    #pragma unroll
    for (int i = 0; i < 4; ++i)
        aSrc[i] = A + (size_t)(bm * 256 + wid * 32 + i * 8 + srow) * K + sch * 8;
    #pragma unroll
    for (int i = 0; i < 2; ++i)
        bSrc[i] = BT + (size_t)(bn * 128 + wid * 16 + i * 8 + srow) * K + sch * 8;

#define GSTAGE(bufi, koff) do {                                              \
        unsigned short* la = (unsigned short*)(ls + (bufi) * 49152);         \
        unsigned short* lb = (unsigned short*)(ls + (bufi) * 49152 + 32768); \
        _Pragma("unroll")                                                    \
        for (int i = 0; i < 4; ++i)                                          \
            gload16(aSrc[i] + (koff), la + (wid * 32 + i * 8) * 64);         \
        _Pragma("unroll")                                                    \
        for (int i = 0; i < 2; ++i)                                          \
            gload16(bSrc[i] + (koff), lb + (wid * 16 + i * 8) * 64);         \
    } while (0)

    GSTAGE(0, 0);

    int ntiles = K >> 6;   // 16
    for (int t = 0; t < ntiles; ++t) {
        int cb = (t & 1) * 49152;
        if (t < ntiles - 1) {
            GSTAGE((t + 1) & 1, (t + 1) * 64);
            asm volatile("s_waitcnt vmcnt(6)" ::: "memory");
        } else {
            asm volatile("s_waitcnt vmcnt(0)" ::: "memory");
        }
        __builtin_amdgcn_s_barrier();
        __builtin_amdgcn_sched_barrier(0);

        const char* la = ls + cb;
        const char* lb = ls + cb + 32768;
        // ---- 4 compute phases: (kk, m-half), 8 MFMA each ----
        #pragma unroll
        for (int kk = 0; kk < 2; ++kk) {
            int chb = ((((kk << 2) + fg) ^ (fr & 7))) << 4;
            u16x8 bf[4];
            #pragma unroll
            for (int n = 0; n < 4; ++n)
                bf[n] = *(const u16x8*)(lb + (wc * 64 + n * 16 + fr) * 128 + chb);
            #pragma unroll
            for (int mh = 0; mh < 2; ++mh) {
                u16x8 af[2];
                #pragma unroll
                for (int m = 0; m < 2; ++m)
                    af[m] = *(const u16x8*)(la + (wr * 64 + (mh * 2 + m) * 16 + fr) * 128 + chb);
                __builtin_amdgcn_sched_barrier(0);
                __builtin_amdgcn_s_setprio(1);
                #pragma unroll
                for (int m = 0; m < 2; ++m)
                    #pragma unroll
                    for (int n = 0; n < 4; ++n)
                        acc[mh * 2 + m][n] = __builtin_amdgcn_mfma_f32_16x16x32_bf16(af[m], bf[n], acc[mh * 2 + m][n], 0, 0, 0);
                __builtin_amdgcn_s_setprio(0);
                if (kk != 1 || mh != 1) {   // no trailing barrier before __syncthreads
                    __builtin_amdgcn_s_barrier();
                    __builtin_amdgcn_sched_barrier(0);
                }
            }
        }

        __syncthreads();   // end-of-tile: drain + publish (validated structure)
    }
#undef GSTAGE

    if (MODE == 0) {
        float* C = (float*)C1;
        #pragma unroll
        for (int n = 0; n < 4; ++n) {
            int col = bn * 128 + wc * 64 + n * 16 + fr;
            float bv = bias[col];
            #pragma unroll
            for (int m = 0; m < 4; ++m) {
                int row0 = bm * 256 + wr * 64 + m * 16 + fg * 4;
                #pragma unroll
                for (int r = 0; r < 4; ++r)
                    C[(size_t)(row0 + r) * N + col] = acc[m][n][r] + bv;
            }
        }
    } else {
        if (bn < 16) {
            unsigned short* qkb = (unsigned short*)C1;
            #pragma unroll
            for (int n = 0; n < 4; ++n) {
                int col = bn * 128 + wc * 64 + n * 16 + fr;
                float bv = bias[col];
                float cs = (col < 1024) ? CQ : 1.0f;
                #pragma unroll
                for (int m = 0; m < 4; ++m) {
                    int row0 = bm * 256 + wr * 64 + m * 16 + fg * 4;
                    #pragma unroll
                    for (int r = 0; r < 4; ++r)
                        qkb[(size_t)(row0 + r) * 2048 + col] = f2bf((acc[m][n][r] + bv) * cs);
                }
            }
        } else {
            unsigned short* vT = (unsigned short*)C2;
            #pragma unroll
            for (int n = 0; n < 4; ++n) {
                int col = bn * 128 + wc * 64 + n * 16 + fr;
                float bv = bias[col];
                int cv = col - 2048;
                int hh = cv >> 6, d = cv & 63;
                #pragma unroll
                for (int m = 0; m < 4; ++m) {
                    int row0 = bm * 256 + wr * 64 + m * 16 + fg * 4;
                    int bb = row0 >> 11, t0 = row0 & 2047;
                    u16x4 st;
                    #pragma unroll
                    for (int r = 0; r < 4; ++r) st[r] = f2bf(acc[m][n][r] + bv);
                    *(u16x4*)&vT[((size_t)((bb * 16 + hh) * 64 + d)) * 2048 + t0] = st;
                }
            }
        }
    }
}

// ---------------- flash attention (round-8 validated kernel) ----------------
__global__ __launch_bounds__(256) void k_attn(const unsigned short* __restrict__ qkb,
                                              const unsigned short* __restrict__ vT,
                                              unsigned short* __restrict__ out) {
    int bid = (blockIdx.x & 7) * 128 + (blockIdx.x >> 3);   // XCD swizzle (1024 blocks)
    int bh = bid >> 4;
    int q0 = (bid & 15) << 7;
    int b = bh >> 4, h = bh & 15;
    int tid = threadIdx.x, wid = tid >> 6, lane = tid & 63;
    int fr = lane & 15, fg = lane >> 4;

    __shared__ unsigned short lK[2][8192];   // K tiles 128x64 (Q 128x64 at init)
    __shared__ unsigned short lV[2][8192];   // V tiles 64x128
    const char* lKb = (const char*)lK;
    const char* lVb = (const char*)lV;

    int srow = lane >> 3;
    int sch  = (lane & 7) ^ srow;
    int woff = wid * 512;

    u16x8 ones;
    #pragma unroll
    for (int i = 0; i < 8; ++i) ones[i] = 0x3F80;  // bf16 1.0

    int kfb[2], vbb[4];
    #pragma unroll
    for (int kk = 0; kk < 2; ++kk) kfb[kk] = fr * 128 + (((((kk << 2) + fg) ^ (fr & 7))) << 4);
    #pragma unroll
    for (int kk = 0; kk < 4; ++kk) vbb[kk] = fr * 256 + (((((kk << 2) + fg) ^ (fr & 7))) << 4);

    const unsigned short* qbase = qkb + (size_t)(b * SEQ) * 2048 + h * 64;
    #pragma unroll
    for (int i = 0; i < 4; ++i) {
        int rbase = i * 32 + wid * 8;
        gload16(qbase + (size_t)(q0 + rbase + srow) * 2048 + sch * 8, (unsigned short*)lK + rbase * 64);
    }
    asm volatile("s_waitcnt vmcnt(0)" ::: "memory");
    __syncthreads();
    u16x8 qf[2][2];
    #pragma unroll
    for (int j = 0; j < 2; ++j)
        #pragma unroll
        for (int kk = 0; kk < 2; ++kk)
            qf[j][kk] = *(const u16x8*)(lKb + kfb[kk] + (wid * 32 + j * 16) * 128);
    __syncthreads();   // all waves done reading Q before K tile0 overwrites lK

    f32x4 o[2][4];
    #pragma unroll
    for (int j = 0; j < 2; ++j)
        #pragma unroll
        for (int i = 0; i < 4; ++i)
            o[j][i] = (f32x4){0.f, 0.f, 0.f, 0.f};
    f32x4 o_sum[2];
    o_sum[0] = (f32x4){0.f, 0.f, 0.f, 0.f};
    o_sum[1] = (f32x4){0.f, 0.f, 0.f, 0.f};

    const unsigned short* kp[4]; const unsigned short* vp[4];
    {
        const unsigned short* kbase = qkb + (size_t)(b * SEQ) * 2048 + 1024 + h * 64;
        const unsigned short* vbase = vT + (size_t)(bh * 64) * SEQ;
        #pragma unroll
        for (int i = 0; i < 4; ++i) {
            kp[i] = kbase + (size_t)(i * 32 + wid * 8 + srow) * 2048 + sch * 8;
            int vrow = i * 16 + wid * 4 + (lane >> 4);
            int vch = (lane & 15) ^ (vrow & 7);
            vp[i] = vbase + (size_t)vrow * SEQ + vch * 8;
        }
    }

#define STAGE(bufi) do {                                                   \
        unsigned short* kd = (unsigned short*)lK + (bufi) * 8192 + woff;   \
        unsigned short* vd = (unsigned short*)lV + (bufi) * 8192 + woff;   \
        _Pragma("unroll")                                                  \
        for (int i = 0; i < 4; ++i) {                                      \
            gload16(kp[i], kd + i * 2048);  kp[i] += 128 * 2048;           \
            gload16(vp[i], vd + i * 2048);  vp[i] += 128;                  \
        }                                                                  \
    } while (0)

    STAGE(0);   // tile 0 -> buf 0

    for (int t = 0; t < 16; ++t) {
        int cur = t & 1;
        int cb = cur * 16384;   // byte offset of current buffer
        if (t < 15) {
            STAGE(cur ^ 1);
            asm volatile("s_waitcnt vmcnt(8)" ::: "memory");
        } else {
            asm volatile("s_waitcnt vmcnt(0)" ::: "memory");
        }
        __builtin_amdgcn_s_barrier();
        __builtin_amdgcn_sched_barrier(0);

        u16x8 pb[2][4];
        #pragma unroll
        for (int ih = 0; ih < 2; ++ih) {
            f32x4 sa[2][4];
            #pragma unroll
            for (int j = 0; j < 2; ++j)
                #pragma unroll
                for (int il = 0; il < 4; ++il)
                    sa[j][il] = (f32x4){0.f, 0.f, 0.f, 0.f};
            #pragma unroll
            for (int kk = 0; kk < 2; ++kk) {
                u16x8 kf[4];
                #pragma unroll
                for (int il = 0; il < 4; ++il)
                    kf[il] = *(const u16x8*)(lKb + cb + kfb[kk] + (ih * 4 + il) * 2048);
                #pragma unroll
                for (int j = 0; j < 2; ++j)
                    #pragma unroll
                    for (int il = 0; il < 4; ++il)
                        sa[j][il] = __builtin_amdgcn_mfma_f32_16x16x32_bf16(kf[il], qf[j][kk], sa[j][il], 0, 0, 0);
            }

            #pragma unroll
            for (int j = 0; j < 2; ++j) {
                unsigned pk[2][2][2];  // [t2=il>>1][il&1][p]
                #pragma unroll
                for (int il = 0; il < 4; ++il) {
                    #pragma unroll
                    for (int p = 0; p < 2; ++p) {
                        float ea = fexp2(sa[j][il][2 * p]);
                        float eb = fexp2(sa[j][il][2 * p + 1]);
                        unsigned rr;
                        asm("v_cvt_pk_bf16_f32 %0, %1, %2" : "=v"(rr) : "v"(ea), "v"(eb));
                        pk[il >> 1][il & 1][p] = rr;
                    }
                }
                #pragma unroll
                for (int t2 = 0; t2 < 2; ++t2) {
                    #pragma unroll
                    for (int p = 0; p < 2; ++p) {
                        asm("v_permlane32_swap_b32 %0, %1" : "+v"(pk[t2][0][p]), "+v"(pk[t2][1][p]));
                        asm("v_permlane16_swap_b32 %0, %1" : "+v"(pk[t2][0][p]), "+v"(pk[t2][1][p]));
                    }
                    union { unsigned u[4]; u16x8 v; } w;
                    w.u[0] = pk[t2][0][0]; w.u[1] = pk[t2][0][1];
                    w.u[2] = pk[t2][1][0]; w.u[3] = pk[t2][1][1];
                    pb[j][ih * 2 + t2] = w.v;
                    o_sum[j] = __builtin_amdgcn_mfma_f32_16x16x32_bf16(ones, pb[j][ih * 2 + t2], o_sum[j], 0, 0, 0);
                }
            }
        }

        #pragma unroll
        for (int kk = 0; kk < 4; ++kk) {
            u16x8 vb[4];
            #pragma unroll
            for (int i = 0; i < 4; ++i)
                vb[i] = *(const u16x8*)(lVb + cb + vbb[kk] + i * 4096);
            #pragma unroll
            for (int j = 0; j < 2; ++j)
                #pragma unroll
                for (int i = 0; i < 4; ++i)
                    o[j][i] = __builtin_amdgcn_mfma_f32_16x16x32_bf16(vb[i], pb[j][kk], o[j][i], 0, 0, 0);
        }

        __syncthreads();   // end-of-tile: drain + publish (validated structure)
    }
#undef STAGE

    #pragma unroll
    for (int j = 0; j < 2; ++j) {
        float inv = 1.f / o_sum[j][0];
        size_t t = q0 + wid * 32 + j * 16 + fr;
        #pragma unroll
        for (int i = 0; i < 4; ++i) {
            u16x4 st;
            st[0] = f2bf(o[j][i][0] * inv);
            st[1] = f2bf(o[j][i][1] * inv);
            st[2] = f2bf(o[j][i][2] * inv);
            st[3] = f2bf(o[j][i][3] * inv);
            *(u16x4*)&out[(size_t)(b * SEQ + t) * HID + h * 64 + i * 16 + fg * 4] = st;
        }
    }
}

extern "C" void kernel_launch(void* const* d_in, const int* in_sizes, int n_in,
                              void* d_out, int out_size, void* d_ws, size_t ws_size,
                              hipStream_t stream) {
    const float* x      = (const float*)d_in[0];
    const float* qkv_w  = (const float*)d_in[1];
    const float* qkv_b  = (const float*)d_in[2];
    const float* proj_w = (const float*)d_in[3];
    const float* proj_b = (const float*)d_in[4];
    float* out = (float*)d_out;

    char* ws = (char*)d_ws;
    unsigned short* xb     = (unsigned short*)ws;                       // 16,777,216 B
    unsigned short* wqkvT  = (unsigned short*)(ws + 16777216);          //  6,291,456 B
    unsigned short* wprojT = (unsigned short*)(ws + 23068672);          //  2,097,152 B
    unsigned short* qkb    = (unsigned short*)(ws + 25165824);          // 33,554,432 B (Q,K)
    unsigned short* vTb    = (unsigned short*)(ws + 58720256);          // 16,777,216 B (V^T)
    unsigned short* aob    = (unsigned short*)(ws + 75497472);          // 16,777,216 B (total 92,274,688)

    // 96 KB dynamic LDS for the 256x128 double-buffered GEMM
    hipFuncSetAttribute(reinterpret_cast<const void*>(&k_gemm<1>),
                        hipFuncAttributeMaxDynamicSharedMemorySize, 98304);
    hipFuncSetAttribute(reinterpret_cast<const void*>(&k_gemm<0>),
                        hipFuncAttributeMaxDynamicSharedMemorySize, 98304);

    k_prep<<<5120, 256, 0, stream>>>(x, xb, qkv_w, wqkvT, proj_w, wprojT);
    k_gemm<1><<<768, 512, 98304, stream>>>(xb, wqkvT, qkv_b, (void*)qkb, (void*)vTb, MTOT, N3, HID);
    k_attn<<<1024, 256, 0, stream>>>(qkb, vTb, aob);
    k_gemm<0><<<256, 512, 98304, stream>>>(aob, wprojT, proj_b, (void*)out, nullptr, MTOT, HID, HID);
}

// Round 14
// 190.615 us; speedup vs baseline: 1.0283x; 1.0283x over previous
//
#include <hip/hip_runtime.h>
#include <hip/hip_bf16.h>

#define HID  1024
#define N3   3072
#define NH   16
#define HD   64
#define SEQ  2048
#define NB   4
#define MTOT 8192

typedef unsigned short u16x8 __attribute__((ext_vector_type(8)));
typedef unsigned short u16x4 __attribute__((ext_vector_type(4)));
typedef float f32x4 __attribute__((ext_vector_type(4)));

static __device__ __forceinline__ unsigned short f2bf(float f) {
    union { float f; unsigned u; } v; v.f = f;
    unsigned r = (v.u + 0x7fffu + ((v.u >> 16) & 1u)) >> 16;
    return (unsigned short)r;
}

static __device__ __forceinline__ float fexp2(float x) {
    float r; asm("v_exp_f32 %0, %1" : "=v"(r) : "v"(x)); return r;
}

typedef __attribute__((address_space(3))) void* lds_vp;
typedef const __attribute__((address_space(1))) void* gbl_vp;

static __device__ __forceinline__ void gload16(const void* g, void* l) {
    __builtin_amdgcn_global_load_lds((gbl_vp)g, (lds_vp)l, 16, 0, 0);
}

// scale * log2(e), folded into GEMM1's Q columns
#define CQ 0.18033688011112042f

// ---------------- merged prep: fp32->bf16 cvt of x + two weight transposes ----
__device__ __forceinline__ void tcvt_tile(const float* __restrict__ W,
                                          unsigned short* __restrict__ WT,
                                          int R, int C, int tile, int tid,
                                          unsigned short* tilebuf) {
    int tiles_c = C >> 6;
    int k0 = (tile / tiles_c) << 6;
    int n0 = (tile % tiles_c) << 6;
    #pragma unroll
    for (int it = 0; it < 2; ++it) {
        int task = it * 256 + tid;
        int t = task >> 3, dc = task & 7;      // t: k-row, dc: n-chunk of 8
        const float* src = W + (size_t)(k0 + t) * C + n0 + dc * 8;
        float4 a = *(const float4*)src;
        float4 b = *(const float4*)(src + 4);
        u16x8 p;
        p[0]=f2bf(a.x); p[1]=f2bf(a.y); p[2]=f2bf(a.z); p[3]=f2bf(a.w);
        p[4]=f2bf(b.x); p[5]=f2bf(b.y); p[6]=f2bf(b.z); p[7]=f2bf(b.w);
        *(u16x8*)&tilebuf[t * 64 + ((dc ^ (t & 7)) << 3)] = p;
    }
    __syncthreads();
    #pragma unroll
    for (int it = 0; it < 2; ++it) {
        int task = it * 256 + tid;
        int d = task >> 3, tc = task & 7;      // d: n index (WT row), tc: k-chunk
        u16x8 p;
        #pragma unroll
        for (int i = 0; i < 8; ++i) {
            int ii = (i + tc) & 7;             // rotate to spread banks
            int t = tc * 8 + ii;
            p[ii] = tilebuf[t * 64 + ((((d >> 3) ^ (t & 7)) << 3)) + (d & 7)];
        }
        *(u16x8*)(WT + (size_t)(n0 + d) * R + k0 + tc * 8) = p;
    }
}

__global__ __launch_bounds__(256) void k_prep(const float* __restrict__ x,
                                              unsigned short* __restrict__ xb,
                                              const float* __restrict__ qkv_w,
                                              unsigned short* __restrict__ wqkvT,
                                              const float* __restrict__ proj_w,
                                              unsigned short* __restrict__ wprojT) {
    __shared__ unsigned short tilebuf[64 * 64];
    int blk = blockIdx.x, tid = threadIdx.x;
    if (blk < 4096) {
        int i = (blk * 256 + tid) * 8;
        float4 a = *(const float4*)(x + i);
        float4 b = *(const float4*)(x + i + 4);
        u16x8 p;
        p[0]=f2bf(a.x); p[1]=f2bf(a.y); p[2]=f2bf(a.z); p[3]=f2bf(a.w);
        p[4]=f2bf(b.x); p[5]=f2bf(b.y); p[6]=f2bf(b.z); p[7]=f2bf(b.w);
        *(u16x8*)(xb + i) = p;
    } else if (blk < 4864) {
        tcvt_tile(qkv_w, wqkvT, HID, N3, blk - 4096, tid, tilebuf);
    } else {
        tcvt_tile(proj_w, wprojT, HID, HID, blk - 4864, tid, tilebuf);
    }
}

// ---------------- GEMM: C[M][N] = A[M][K] * BT[N][K]^T + bias ----------------
// 256x128 tile, 8 waves (4m x 2n), BK=64, double-buffered dynamic LDS (96 KB).
// Skeleton (validated r12): STAGE(next) -> counted vmcnt(6) -> s_barrier ->
// compute -> __syncthreads.  (r13's phase-split regressed; reverted.)
// MODE 0: f32 output to C1 (proj GEMM)
// MODE 1: qkv split -- cols<2048 -> bf16 qkb[row][2048] (cols<1024 scaled by CQ);
//         cols>=2048 -> bf16 vT[(b*16+h)*64+d][t] (V transposed in epilogue)
template<int MODE>
__global__ __launch_bounds__(512, 2) void k_gemm(const unsigned short* __restrict__ A,
                                                 const unsigned short* __restrict__ BT,
                                                 const float* __restrict__ bias,
                                                 void* __restrict__ C1, void* __restrict__ C2,
                                                 int M, int N, int K) {
    extern __shared__ char ls[];   // [2][ A 256x64 (32KB) + B 128x64 (16KB) ]
    int tiles_n = N >> 7;
    // XCD-aware bijective swizzle (gridDim.x % 8 == 0 for all our launches)
    int bid = (blockIdx.x & 7) * (gridDim.x >> 3) + (blockIdx.x >> 3);
    int bm = bid / tiles_n, bn = bid % tiles_n;
    int tid = threadIdx.x, wid = tid >> 6, lane = tid & 63;
    int wr = wid >> 1, wc = wid & 1;
    int fr = lane & 15, fg = lane >> 4;
    int srow = lane >> 3;                    // 0..7
    int sch  = (lane & 7) ^ srow;            // swizzled k-chunk in global

    f32x4 acc[4][4];
    #pragma unroll
    for (int m = 0; m < 4; ++m)
        #pragma unroll
        for (int n = 0; n < 4; ++n)
            acc[m][n] = (f32x4){0.f, 0.f, 0.f, 0.f};

    const unsigned short* aSrc[4]; const unsigned short* bSrc[2];
    #pragma unroll
    for (int i = 0; i < 4; ++i)
        aSrc[i] = A + (size_t)(bm * 256 + wid * 32 + i * 8 + srow) * K + sch * 8;
    #pragma unroll
    for (int i = 0; i < 2; ++i)
        bSrc[i] = BT + (size_t)(bn * 128 + wid * 16 + i * 8 + srow) * K + sch * 8;

#define GSTAGE(bufi, koff) do {                                              \
        unsigned short* la = (unsigned short*)(ls + (bufi) * 49152);         \
        unsigned short* lb = (unsigned short*)(ls + (bufi) * 49152 + 32768); \
        _Pragma("unroll")                                                    \
        for (int i = 0; i < 4; ++i)                                          \
            gload16(aSrc[i] + (koff), la + (wid * 32 + i * 8) * 64);         \
        _Pragma("unroll")                                                    \
        for (int i = 0; i < 2; ++i)                                          \
            gload16(bSrc[i] + (koff), lb + (wid * 16 + i * 8) * 64);         \
    } while (0)

    GSTAGE(0, 0);

    int ntiles = K >> 6;   // 16
    for (int t = 0; t < ntiles; ++t) {
        int cb = (t & 1) * 49152;
        if (t < ntiles - 1) {
            GSTAGE((t + 1) & 1, (t + 1) * 64);
            asm volatile("s_waitcnt vmcnt(6)" ::: "memory");
        } else {
            asm volatile("s_waitcnt vmcnt(0)" ::: "memory");
        }
        __builtin_amdgcn_s_barrier();
        __builtin_amdgcn_sched_barrier(0);

        const char* la = ls + cb;
        const char* lb = ls + cb + 32768;
        #pragma unroll
        for (int kk = 0; kk < 2; ++kk) {
            u16x8 af[4], bf[4];
            int chb = ((((kk << 2) + fg) ^ (fr & 7))) << 4;
            #pragma unroll
            for (int m = 0; m < 4; ++m)
                af[m] = *(const u16x8*)(la + (wr * 64 + m * 16 + fr) * 128 + chb);
            #pragma unroll
            for (int n = 0; n < 4; ++n)
                bf[n] = *(const u16x8*)(lb + (wc * 64 + n * 16 + fr) * 128 + chb);
            #pragma unroll
            for (int m = 0; m < 4; ++m)
                #pragma unroll
                for (int n = 0; n < 4; ++n)
                    acc[m][n] = __builtin_amdgcn_mfma_f32_16x16x32_bf16(af[m], bf[n], acc[m][n], 0, 0, 0);
        }

        __syncthreads();   // end-of-tile: drain + publish (validated structure)
    }
#undef GSTAGE

    if (MODE == 0) {
        float* C = (float*)C1;
        #pragma unroll
        for (int n = 0; n < 4; ++n) {
            int col = bn * 128 + wc * 64 + n * 16 + fr;
            float bv = bias[col];
            #pragma unroll
            for (int m = 0; m < 4; ++m) {
                int row0 = bm * 256 + wr * 64 + m * 16 + fg * 4;
                #pragma unroll
                for (int r = 0; r < 4; ++r)
                    C[(size_t)(row0 + r) * N + col] = acc[m][n][r] + bv;
            }
        }
    } else {
        if (bn < 16) {
            unsigned short* qkb = (unsigned short*)C1;
            #pragma unroll
            for (int n = 0; n < 4; ++n) {
                int col = bn * 128 + wc * 64 + n * 16 + fr;
                float bv = bias[col];
                float cs = (col < 1024) ? CQ : 1.0f;
                #pragma unroll
                for (int m = 0; m < 4; ++m) {
                    int row0 = bm * 256 + wr * 64 + m * 16 + fg * 4;
                    #pragma unroll
                    for (int r = 0; r < 4; ++r)
                        qkb[(size_t)(row0 + r) * 2048 + col] = f2bf((acc[m][n][r] + bv) * cs);
                }
            }
        } else {
            unsigned short* vT = (unsigned short*)C2;
            #pragma unroll
            for (int n = 0; n < 4; ++n) {
                int col = bn * 128 + wc * 64 + n * 16 + fr;
                float bv = bias[col];
                int cv = col - 2048;
                int hh = cv >> 6, d = cv & 63;
                #pragma unroll
                for (int m = 0; m < 4; ++m) {
                    int row0 = bm * 256 + wr * 64 + m * 16 + fg * 4;
                    int bb = row0 >> 11, t0 = row0 & 2047;
                    u16x4 st;
                    #pragma unroll
                    for (int r = 0; r < 4; ++r) st[r] = f2bf(acc[m][n][r] + bv);
                    *(u16x4*)&vT[((size_t)((bb * 16 + hh) * 64 + d)) * 2048 + t0] = st;
                }
            }
        }
    }
}

// ---------------- flash attention (round-8 validated kernel) ----------------
__global__ __launch_bounds__(256) void k_attn(const unsigned short* __restrict__ qkb,
                                              const unsigned short* __restrict__ vT,
                                              unsigned short* __restrict__ out) {
    int bid = (blockIdx.x & 7) * 128 + (blockIdx.x >> 3);   // XCD swizzle (1024 blocks)
    int bh = bid >> 4;
    int q0 = (bid & 15) << 7;
    int b = bh >> 4, h = bh & 15;
    int tid = threadIdx.x, wid = tid >> 6, lane = tid & 63;
    int fr = lane & 15, fg = lane >> 4;

    __shared__ unsigned short lK[2][8192];   // K tiles 128x64 (Q 128x64 at init)
    __shared__ unsigned short lV[2][8192];   // V tiles 64x128
    const char* lKb = (const char*)lK;
    const char* lVb = (const char*)lV;

    int srow = lane >> 3;
    int sch  = (lane & 7) ^ srow;
    int woff = wid * 512;

    u16x8 ones;
    #pragma unroll
    for (int i = 0; i < 8; ++i) ones[i] = 0x3F80;  // bf16 1.0

    int kfb[2], vbb[4];
    #pragma unroll
    for (int kk = 0; kk < 2; ++kk) kfb[kk] = fr * 128 + (((((kk << 2) + fg) ^ (fr & 7))) << 4);
    #pragma unroll
    for (int kk = 0; kk < 4; ++kk) vbb[kk] = fr * 256 + (((((kk << 2) + fg) ^ (fr & 7))) << 4);

    const unsigned short* qbase = qkb + (size_t)(b * SEQ) * 2048 + h * 64;
    #pragma unroll
    for (int i = 0; i < 4; ++i) {
        int rbase = i * 32 + wid * 8;
        gload16(qbase + (size_t)(q0 + rbase + srow) * 2048 + sch * 8, (unsigned short*)lK + rbase * 64);
    }
    asm volatile("s_waitcnt vmcnt(0)" ::: "memory");
    __syncthreads();
    u16x8 qf[2][2];
    #pragma unroll
    for (int j = 0; j < 2; ++j)
        #pragma unroll
        for (int kk = 0; kk < 2; ++kk)
            qf[j][kk] = *(const u16x8*)(lKb + kfb[kk] + (wid * 32 + j * 16) * 128);
    __syncthreads();   // all waves done reading Q before K tile0 overwrites lK

    f32x4 o[2][4];
    #pragma unroll
    for (int j = 0; j < 2; ++j)
        #pragma unroll
        for (int i = 0; i < 4; ++i)
            o[j][i] = (f32x4){0.f, 0.f, 0.f, 0.f};
    f32x4 o_sum[2];
    o_sum[0] = (f32x4){0.f, 0.f, 0.f, 0.f};
    o_sum[1] = (f32x4){0.f, 0.f, 0.f, 0.f};

    const unsigned short* kp[4]; const unsigned short* vp[4];
    {
        const unsigned short* kbase = qkb + (size_t)(b * SEQ) * 2048 + 1024 + h * 64;
        const unsigned short* vbase = vT + (size_t)(bh * 64) * SEQ;
        #pragma unroll
        for (int i = 0; i < 4; ++i) {
            kp[i] = kbase + (size_t)(i * 32 + wid * 8 + srow) * 2048 + sch * 8;
            int vrow = i * 16 + wid * 4 + (lane >> 4);
            int vch = (lane & 15) ^ (vrow & 7);
            vp[i] = vbase + (size_t)vrow * SEQ + vch * 8;
        }
    }

#define STAGE(bufi) do {                                                   \
        unsigned short* kd = (unsigned short*)lK + (bufi) * 8192 + woff;   \
        unsigned short* vd = (unsigned short*)lV + (bufi) * 8192 + woff;   \
        _Pragma("unroll")                                                  \
        for (int i = 0; i < 4; ++i) {                                      \
            gload16(kp[i], kd + i * 2048);  kp[i] += 128 * 2048;           \
            gload16(vp[i], vd + i * 2048);  vp[i] += 128;                  \
        }                                                                  \
    } while (0)

    STAGE(0);   // tile 0 -> buf 0

    for (int t = 0; t < 16; ++t) {
        int cur = t & 1;
        int cb = cur * 16384;   // byte offset of current buffer
        if (t < 15) {
            STAGE(cur ^ 1);
            asm volatile("s_waitcnt vmcnt(8)" ::: "memory");
        } else {
            asm volatile("s_waitcnt vmcnt(0)" ::: "memory");
        }
        __builtin_amdgcn_s_barrier();
        __builtin_amdgcn_sched_barrier(0);

        u16x8 pb[2][4];
        #pragma unroll
        for (int ih = 0; ih < 2; ++ih) {
            f32x4 sa[2][4];
            #pragma unroll
            for (int j = 0; j < 2; ++j)
                #pragma unroll
                for (int il = 0; il < 4; ++il)
                    sa[j][il] = (f32x4){0.f, 0.f, 0.f, 0.f};
            #pragma unroll
            for (int kk = 0; kk < 2; ++kk) {
                u16x8 kf[4];
                #pragma unroll
                for (int il = 0; il < 4; ++il)
                    kf[il] = *(const u16x8*)(lKb + cb + kfb[kk] + (ih * 4 + il) * 2048);
                #pragma unroll
                for (int j = 0; j < 2; ++j)
                    #pragma unroll
                    for (int il = 0; il < 4; ++il)
                        sa[j][il] = __builtin_amdgcn_mfma_f32_16x16x32_bf16(kf[il], qf[j][kk], sa[j][il], 0, 0, 0);
            }

            #pragma unroll
            for (int j = 0; j < 2; ++j) {
                unsigned pk[2][2][2];  // [t2=il>>1][il&1][p]
                #pragma unroll
                for (int il = 0; il < 4; ++il) {
                    #pragma unroll
                    for (int p = 0; p < 2; ++p) {
                        float ea = fexp2(sa[j][il][2 * p]);
                        float eb = fexp2(sa[j][il][2 * p + 1]);
                        unsigned rr;
                        asm("v_cvt_pk_bf16_f32 %0, %1, %2" : "=v"(rr) : "v"(ea), "v"(eb));
                        pk[il >> 1][il & 1][p] = rr;
                    }
                }
                #pragma unroll
                for (int t2 = 0; t2 < 2; ++t2) {
                    #pragma unroll
                    for (int p = 0; p < 2; ++p) {
                        asm("v_permlane32_swap_b32 %0, %1" : "+v"(pk[t2][0][p]), "+v"(pk[t2][1][p]));
                        asm("v_permlane16_swap_b32 %0, %1" : "+v"(pk[t2][0][p]), "+v"(pk[t2][1][p]));
                    }
                    union { unsigned u[4]; u16x8 v; } w;
                    w.u[0] = pk[t2][0][0]; w.u[1] = pk[t2][0][1];
                    w.u[2] = pk[t2][1][0]; w.u[3] = pk[t2][1][1];
                    pb[j][ih * 2 + t2] = w.v;
                    o_sum[j] = __builtin_amdgcn_mfma_f32_16x16x32_bf16(ones, pb[j][ih * 2 + t2], o_sum[j], 0, 0, 0);
                }
            }
        }

        #pragma unroll
        for (int kk = 0; kk < 4; ++kk) {
            u16x8 vb[4];
            #pragma unroll
            for (int i = 0; i < 4; ++i)
                vb[i] = *(const u16x8*)(lVb + cb + vbb[kk] + i * 4096);
            #pragma unroll
            for (int j = 0; j < 2; ++j)
                #pragma unroll
                for (int i = 0; i < 4; ++i)
                    o[j][i] = __builtin_amdgcn_mfma_f32_16x16x32_bf16(vb[i], pb[j][kk], o[j][i], 0, 0, 0);
        }

        __syncthreads();   // end-of-tile: drain + publish (validated structure)
    }
#undef STAGE

    #pragma unroll
    for (int j = 0; j < 2; ++j) {
        float inv = 1.f / o_sum[j][0];
        size_t t = q0 + wid * 32 + j * 16 + fr;
        #pragma unroll
        for (int i = 0; i < 4; ++i) {
            u16x4 st;
            st[0] = f2bf(o[j][i][0] * inv);
            st[1] = f2bf(o[j][i][1] * inv);
            st[2] = f2bf(o[j][i][2] * inv);
            st[3] = f2bf(o[j][i][3] * inv);
            *(u16x4*)&out[(size_t)(b * SEQ + t) * HID + h * 64 + i * 16 + fg * 4] = st;
        }
    }
}

extern "C" void kernel_launch(void* const* d_in, const int* in_sizes, int n_in,
                              void* d_out, int out_size, void* d_ws, size_t ws_size,
                              hipStream_t stream) {
    const float* x      = (const float*)d_in[0];
    const float* qkv_w  = (const float*)d_in[1];
    const float* qkv_b  = (const float*)d_in[2];
    const float* proj_w = (const float*)d_in[3];
    const float* proj_b = (const float*)d_in[4];
    float* out = (float*)d_out;

    char* ws = (char*)d_ws;
    unsigned short* xb     = (unsigned short*)ws;                       // 16,777,216 B
    unsigned short* wqkvT  = (unsigned short*)(ws + 16777216);          //  6,291,456 B
    unsigned short* wprojT = (unsigned short*)(ws + 23068672);          //  2,097,152 B
    unsigned short* qkb    = (unsigned short*)(ws + 25165824);          // 33,554,432 B (Q,K)
    unsigned short* vTb    = (unsigned short*)(ws + 58720256);          // 16,777,216 B (V^T)
    unsigned short* aob    = (unsigned short*)(ws + 75497472);          // 16,777,216 B (total 92,274,688)

    // 96 KB dynamic LDS for the 256x128 double-buffered GEMM
    hipFuncSetAttribute(reinterpret_cast<const void*>(&k_gemm<1>),
                        hipFuncAttributeMaxDynamicSharedMemorySize, 98304);
    hipFuncSetAttribute(reinterpret_cast<const void*>(&k_gemm<0>),
                        hipFuncAttributeMaxDynamicSharedMemorySize, 98304);

    k_prep<<<5120, 256, 0, stream>>>(x, xb, qkv_w, wqkvT, proj_w, wprojT);
    k_gemm<1><<<768, 512, 98304, stream>>>(xb, wqkvT, qkv_b, (void*)qkb, (void*)vTb, MTOT, N3, HID);
    k_attn<<<1024, 256, 0, stream>>>(qkb, vTb, aob);
    k_gemm<0><<<256, 512, 98304, stream>>>(aob, wprojT, proj_b, (void*)out, nullptr, MTOT, HID, HID);
}